// Round 1
// baseline (1326.602 us; speedup 1.0000x reference)
//
#include <hip/hip_runtime.h>

#define NEG_INF (-__builtin_inff())

__device__ __forceinline__ float dot4acc(float4 a, float4 b, float acc) {
  acc = fmaf(a.x, b.x, acc);
  acc = fmaf(a.y, b.y, acc);
  acc = fmaf(a.z, b.z, acc);
  acc = fmaf(a.w, b.w, acc);
  return acc;
}

// ---------------------------------------------------------------------------
// Projection GEMM: out = X(M,512) @ W(512,512)^T + bias
// mode 0: out[((b*8+h)*1024 + t)*64 + d]   (B,H,T,D) layout; b = n>>10
// mode 1: out[n*512 + fo]                  plain row-major
// ---------------------------------------------------------------------------
__global__ __launch_bounds__(256) void proj_gemm(
    const float* __restrict__ X, const float* __restrict__ W,
    const float* __restrict__ bias, float* __restrict__ out,
    int M, int mode)
{
  __shared__ float As[32][72];   // k-major, pad 72: 2-way max on reads/writes
  __shared__ float Bs[32][72];
  const int tid = threadIdx.x;
  const int row0 = blockIdx.x * 64;
  const int col0 = blockIdx.y * 64;
  const int tm0 = (tid & 15) * 4;
  const int tn0 = (tid >> 4) * 4;
  float acc[4][4] = {};

  for (int k0 = 0; k0 < 512; k0 += 32) {
#pragma unroll
    for (int q = 0; q < 2; ++q) {
      int idx = q * 256 + tid;
      int r = idx >> 3, c4 = idx & 7;
      float4 a = *(const float4*)&X[(size_t)(row0 + r) * 512 + k0 + c4 * 4];
      As[c4*4+0][r] = a.x; As[c4*4+1][r] = a.y;
      As[c4*4+2][r] = a.z; As[c4*4+3][r] = a.w;
      float4 b = *(const float4*)&W[(size_t)(col0 + r) * 512 + k0 + c4 * 4];
      Bs[c4*4+0][r] = b.x; Bs[c4*4+1][r] = b.y;
      Bs[c4*4+2][r] = b.z; Bs[c4*4+3][r] = b.w;
    }
    __syncthreads();
#pragma unroll
    for (int kk = 0; kk < 32; ++kk) {
      float4 av = *(const float4*)&As[kk][tm0];
      float4 bv = *(const float4*)&Bs[kk][tn0];
      float a_[4] = {av.x, av.y, av.z, av.w};
      float b_[4] = {bv.x, bv.y, bv.z, bv.w};
#pragma unroll
      for (int i = 0; i < 4; ++i)
#pragma unroll
        for (int j = 0; j < 4; ++j)
          acc[i][j] = fmaf(a_[i], b_[j], acc[i][j]);
    }
    __syncthreads();
  }

  float4 bb = make_float4(0.f, 0.f, 0.f, 0.f);
  if (bias) bb = *(const float4*)&bias[col0 + tn0];
#pragma unroll
  for (int i = 0; i < 4; ++i) {
    int n = row0 + tm0 + i;
    float4 res = make_float4(acc[i][0] + bb.x, acc[i][1] + bb.y,
                             acc[i][2] + bb.z, acc[i][3] + bb.w);
    size_t off;
    if (mode == 0) {
      int bI = n >> 10, t = n & 1023, hI = col0 >> 6;
      off = ((size_t)(bI * 8 + hI) * 1024 + t) * 64 + tn0;
    } else {
      off = (size_t)n * 512 + col0 + tn0;
    }
    *(float4*)&out[off] = res;
  }
}

// ---------------------------------------------------------------------------
// Fused attention for one (b,h) x 8 query rows per block.
// scores[t][s] = ( (Q[t]+u)·K[s] + (Q[t]+v)·P[s] ) / 8   (128-wide dot)
// masked softmax (mask==0 -> -inf -> 0), then O = attn @ V.
// ---------------------------------------------------------------------------
__global__ __launch_bounds__(256) void attn_kernel(
    const float* __restrict__ Q, const float* __restrict__ K,
    const float* __restrict__ P, const float* __restrict__ V,
    const int* __restrict__ mask,
    const float* __restrict__ ubias, const float* __restrict__ vbias,
    float* __restrict__ X)
{
  __shared__ float scratch[2048];   // Qs[8][132] (phase 1), Opart[4][8][64] (phase 3)
  __shared__ float Ks[64][128];     // K|P tile, XOR-swizzled (quad ^= row&7)
  __shared__ float S[8][1024];      // score / attn rows
  __shared__ float rowscale[8];

  const int tid = threadIdx.x;
  const int bh = blockIdx.y, b = bh >> 3, h = bh & 7;
  const int t0g = blockIdx.x * 8;

  const float* Qg = Q + ((size_t)bh * 1024 + t0g) * 64;
  const float* Kg = K + (size_t)bh * 1024 * 64;
  const float* Pg = P + (size_t)h * 1024 * 64;
  const float* Vg = V + (size_t)bh * 1024 * 64;
  const int*  maskb = mask + (size_t)b * 1024 * 1024 + (size_t)t0g * 1024;

  // ---- load 8 Q rows, pre-add u (cols 0..63) and v (cols 64..127)
  float* Qs = scratch;              // viewed as [8][132]
  if (tid < 128) {
    int r = tid >> 4, c4 = tid & 15;
    float4 q = *(const float4*)&Qg[r * 64 + c4 * 4];
    float4 u = *(const float4*)&ubias[h * 64 + c4 * 4];
    float4 v = *(const float4*)&vbias[h * 64 + c4 * 4];
    float* row = &Qs[r * 132];
    row[c4*4+0] = q.x + u.x; row[c4*4+1] = q.y + u.y;
    row[c4*4+2] = q.z + u.z; row[c4*4+3] = q.w + u.w;
    row[64+c4*4+0] = q.x + v.x; row[64+c4*4+1] = q.y + v.y;
    row[64+c4*4+2] = q.z + v.z; row[64+c4*4+3] = q.w + v.w;
  }

  // phase-1 thread mapping: micro 2t x 2s, d split across lane pairs
  const int dpart = tid & 1;
  const int mid = tid >> 1;
  const int sm = mid & 31;          // s within tile: {sm, sm+32}
  const int t0 = (mid >> 5) * 2;    // per-wave t-pair
  const int e = sm & 7;             // swizzle key (same for sm and sm+32)
  const float4* Qs4 = (const float4*)Qs;      // row stride 33 quads
  const float4* Ks4 = (const float4*)&Ks[0][0];

  for (int s0 = 0; s0 < 1024; s0 += 64) {
    // stage K|P tile (swizzled)
#pragma unroll
    for (int q = 0; q < 4; ++q) {
      int idx = q * 256 + tid;
      int r = idx >> 4, c4 = idx & 15;
      int sq = c4 ^ (r & 7);
      *(float4*)&Ks[r][sq * 4]      = *(const float4*)&Kg[(size_t)(s0 + r) * 64 + c4 * 4];
      *(float4*)&Ks[r][64 + sq * 4] = *(const float4*)&Pg[(size_t)(s0 + r) * 64 + c4 * 4];
    }
    __syncthreads();

    float a00 = 0.f, a01 = 0.f, a10 = 0.f, a11 = 0.f;
#pragma unroll
    for (int j = 0; j < 16; ++j) {
      int dq = dpart + 2 * j;                       // logical d-quad 0..31
      int phys = (dq & 16) | ((dq & 15) ^ e);       // unswizzle for K|P
      float4 q0 = Qs4[t0 * 33 + dq];
      float4 q1 = Qs4[(t0 + 1) * 33 + dq];
      float4 k0 = Ks4[sm * 32 + phys];
      float4 k1 = Ks4[(sm + 32) * 32 + phys];
      a00 = dot4acc(q0, k0, a00);
      a01 = dot4acc(q0, k1, a01);
      a10 = dot4acc(q1, k0, a10);
      a11 = dot4acc(q1, k1, a11);
    }
    // combine d-halves across lane pairs
    a00 += __shfl_xor(a00, 1);
    a01 += __shfl_xor(a01, 1);
    a10 += __shfl_xor(a10, 1);
    a11 += __shfl_xor(a11, 1);

    int s_g = s0 + sm + 32 * dpart;
    float v0 = dpart ? a01 : a00;
    float v1 = dpart ? a11 : a10;
    int m0 = maskb[(t0) * 1024 + s_g];
    int m1 = maskb[(t0 + 1) * 1024 + s_g];
    S[t0][s_g]     = m0 ? v0 * 0.125f : NEG_INF;
    S[t0 + 1][s_g] = m1 ? v1 * 0.125f : NEG_INF;
    __syncthreads();
  }

  // ---- phase 2: masked softmax per row (32 lanes per row)
  {
    const int t = tid >> 5, sl = tid & 31;
    float m = NEG_INF;
#pragma unroll 8
    for (int i = 0; i < 32; ++i) m = fmaxf(m, S[t][sl + 32 * i]);
#pragma unroll
    for (int off = 16; off > 0; off >>= 1) m = fmaxf(m, __shfl_xor(m, off));
    float sum = 0.f;
#pragma unroll 8
    for (int i = 0; i < 32; ++i) {
      float x = S[t][sl + 32 * i];
      float p = (x == NEG_INF) ? 0.f : __expf(x - m);
      S[t][sl + 32 * i] = p;
      sum += p;
    }
#pragma unroll
    for (int off = 16; off > 0; off >>= 1) sum += __shfl_xor(sum, off);
    if (sl == 0) rowscale[t] = (sum > 0.f) ? 1.f / sum : 0.f;
  }
  __syncthreads();

  // ---- phase 3: O = attn @ V ; V streamed from L2; micro 2t x 4d,
  //      s-range split over the 4 waves, partials combined via LDS.
  {
    const int dq = tid & 15;
    const int tp = (tid >> 4) & 3;
    const int w = tid >> 6;
    const int ta = tp * 2;
    const float4* V4 = (const float4*)Vg;
    const float* S0 = &S[ta][0];
    const float* S1 = &S[ta + 1][0];
    float4 acc0 = make_float4(0,0,0,0), acc1 = make_float4(0,0,0,0);
    const int sbeg = w * 256;
#pragma unroll 4
    for (int s = sbeg; s < sbeg + 256; ++s) {
      float4 vv = V4[(size_t)s * 16 + dq];
      float p0 = S0[s], p1 = S1[s];
      acc0.x = fmaf(p0, vv.x, acc0.x); acc0.y = fmaf(p0, vv.y, acc0.y);
      acc0.z = fmaf(p0, vv.z, acc0.z); acc0.w = fmaf(p0, vv.w, acc0.w);
      acc1.x = fmaf(p1, vv.x, acc1.x); acc1.y = fmaf(p1, vv.y, acc1.y);
      acc1.z = fmaf(p1, vv.z, acc1.z); acc1.w = fmaf(p1, vv.w, acc1.w);
    }
    float* Op = scratch;   // Qs is dead now
    *(float4*)&Op[((w * 8) + ta) * 64 + dq * 4] = acc0;
    *(float4*)&Op[((w * 8) + ta + 1) * 64 + dq * 4] = acc1;
  }
  __syncthreads();
  {
    const int t = tid >> 5;
    const int d0 = (tid & 31) * 2;
    const float* Op = scratch;
    float r0 = 0.f, r1 = 0.f;
#pragma unroll
    for (int ww = 0; ww < 4; ++ww) {
      r0 += Op[(ww * 8 + t) * 64 + d0];
      r1 += Op[(ww * 8 + t) * 64 + d0 + 1];
    }
    float sc = rowscale[t];
    float2 res = make_float2(r0 * sc, r1 * sc);
    *(float2*)&X[((size_t)b * 1024 + t0g + t) * 512 + h * 64 + d0] = res;
  }
}

extern "C" void kernel_launch(void* const* d_in, const int* in_sizes, int n_in,
                              void* d_out, int out_size, void* d_ws, size_t ws_size,
                              hipStream_t stream) {
  const float* query = (const float*)d_in[0];
  const float* key   = (const float*)d_in[1];
  const float* value = (const float*)d_in[2];
  const int*   mask  = (const int*)d_in[3];
  const float* pos   = (const float*)d_in[4];
  const float* Wq = (const float*)d_in[5];
  const float* bq = (const float*)d_in[6];
  const float* Wk = (const float*)d_in[7];
  const float* bk = (const float*)d_in[8];
  const float* Wv = (const float*)d_in[9];
  const float* bv = (const float*)d_in[10];
  const float* Wp = (const float*)d_in[11];
  const float* Wo = (const float*)d_in[12];
  const float* bo = (const float*)d_in[13];
  const float* ub = (const float*)d_in[14];
  const float* vb = (const float*)d_in[15];
  float* out = (float*)d_out;

  float* ws  = (float*)d_ws;
  float* wsQ = ws;                                   // (B,H,T,64)
  float* wsK = wsQ + (size_t)8 * 8 * 1024 * 64;      // (B,H,T,64)
  float* wsV = wsK + (size_t)8 * 8 * 1024 * 64;      // (B,H,T,64)
  float* wsP = wsV + (size_t)8 * 8 * 1024 * 64;      // (H,T,64)
  float* wsX = wsP + (size_t)8 * 1024 * 64;          // (B,T,512)

  dim3 blk(256);
  proj_gemm<<<dim3(128, 8), blk, 0, stream>>>(query, Wq, bq, wsQ, 8192, 0);
  proj_gemm<<<dim3(128, 8), blk, 0, stream>>>(key,   Wk, bk, wsK, 8192, 0);
  proj_gemm<<<dim3(128, 8), blk, 0, stream>>>(value, Wv, bv, wsV, 8192, 0);
  proj_gemm<<<dim3(16, 8),  blk, 0, stream>>>(pos,   Wp, nullptr, wsP, 1024, 0);
  attn_kernel<<<dim3(128, 64), blk, 0, stream>>>(wsQ, wsK, wsP, wsV, mask, ub, vb, wsX);
  proj_gemm<<<dim3(128, 8), blk, 0, stream>>>(wsX, Wo, bo, out, 8192, 1);
}

// Round 6
// 313.664 us; speedup vs baseline: 4.2294x; 4.2294x over previous
//
#include <hip/hip_runtime.h>

typedef float f32x4 __attribute__((ext_vector_type(4)));
typedef short bf16x8 __attribute__((ext_vector_type(8)));
typedef unsigned short u16x8 __attribute__((ext_vector_type(8)));

__device__ __forceinline__ unsigned short f2bf(float f) {
  union { float f; unsigned int u; } c; c.f = f;
  unsigned int r = (c.u + 0x7fffu + ((c.u >> 16) & 1u)) >> 16;
  return (unsigned short)r;
}
__device__ __forceinline__ float bf2f(unsigned short u) {
  union { unsigned int u; float f; } c; c.u = ((unsigned int)u) << 16;
  return c.f;
}

// ---------------------------------------------------------------------------
// fp32 -> bf16 weight conversion, 5 segments (Wq,Wk,Wv,Wp,Wo), 512x512 each
// ---------------------------------------------------------------------------
struct CvtWArgs {
  const float* s[5];
  unsigned short* d[5];
};

__global__ __launch_bounds__(256) void cvt_w(CvtWArgs a) {
  const int seg = blockIdx.y;
  const float* __restrict__ src = a.s[seg];
  unsigned short* __restrict__ dst = a.d[seg];
  int i = (blockIdx.x * 256 + threadIdx.x) * 8;   // grid.x=128 -> i < 262144 exact
  float4 v0 = *(const float4*)&src[i];
  float4 v1 = *(const float4*)&src[i + 4];
  u16x8 o;
  o[0] = f2bf(v0.x); o[1] = f2bf(v0.y); o[2] = f2bf(v0.z); o[3] = f2bf(v0.w);
  o[4] = f2bf(v1.x); o[5] = f2bf(v1.y); o[6] = f2bf(v1.z); o[7] = f2bf(v1.w);
  *(u16x8*)&dst[i] = o;
}

// ---------------------------------------------------------------------------
// mask (int32, B*T*T) -> packed bits (1 = keep)
// ---------------------------------------------------------------------------
__global__ __launch_bounds__(256) void pack_mask(const int* __restrict__ mask,
                                                 unsigned long long* __restrict__ bits) {
  size_t i = (size_t)blockIdx.x * 256 + threadIdx.x;
  unsigned long long b = __ballot(mask[i] != 0);
  if ((threadIdx.x & 63) == 0) bits[i >> 6] = b;
}

// ---------------------------------------------------------------------------
// bf16 MFMA projection GEMM: out = X(M,512) @ W(512,512)^T (+bias)
// tile 128x64, 4 waves (2x2), wave tile 64x32, BK=64, XOR-swizzled LDS.
// IN_FP32: X is fp32 (converted to bf16 during LDS staging); else bf16.
// MODE 0: out[((b*8+h)*1024+t)*64+d] (B,H,T,D); MODE 1: row-major (M,512)
// ---------------------------------------------------------------------------
template <int IN_FP32, typename OT, int MODE>
__global__ __launch_bounds__(256) void proj_mfma(
    const void* __restrict__ Xv, const unsigned short* __restrict__ W,
    const float* __restrict__ bias, OT* __restrict__ out)
{
  __shared__ unsigned short AL[128 * 64];
  __shared__ unsigned short BL[64 * 64];
  const int tid = threadIdx.x;
  const int lane = tid & 63, wv = tid >> 6;
  const int lg = lane >> 4, lr = lane & 15;
  const int wm = wv >> 1, wn = wv & 1;
  const int row0 = blockIdx.x * 128, col0 = blockIdx.y * 64;

  f32x4 acc[4][2];
#pragma unroll
  for (int i = 0; i < 4; ++i)
#pragma unroll
    for (int j = 0; j < 2; ++j) { f32x4 z = {0.f,0.f,0.f,0.f}; acc[i][j] = z; }

  for (int k0 = 0; k0 < 512; k0 += 64) {
    __syncthreads();
    // ---- stage A tile (128 x 64), swizzled: unit u -> u ^ (r&7)
    if constexpr (IN_FP32) {
      const float* X = (const float*)Xv;
#pragma unroll
      for (int j = 0; j < 4; ++j) {
        int idx = j * 256 + tid;
        int r = idx >> 3, u = idx & 7;
        const float* p = &X[(size_t)(row0 + r) * 512 + k0 + u * 8];
        float4 x0 = *(const float4*)p;
        float4 x1 = *(const float4*)(p + 4);
        u16x8 o;
        o[0] = f2bf(x0.x); o[1] = f2bf(x0.y); o[2] = f2bf(x0.z); o[3] = f2bf(x0.w);
        o[4] = f2bf(x1.x); o[5] = f2bf(x1.y); o[6] = f2bf(x1.z); o[7] = f2bf(x1.w);
        *(u16x8*)&AL[r * 64 + ((u ^ (r & 7)) << 3)] = o;
      }
    } else {
      const unsigned short* X = (const unsigned short*)Xv;
#pragma unroll
      for (int j = 0; j < 4; ++j) {
        int idx = j * 256 + tid;
        int r = idx >> 3, u = idx & 7;
        uint4 v = *(const uint4*)&X[(size_t)(row0 + r) * 512 + k0 + u * 8];
        *(uint4*)&AL[r * 64 + ((u ^ (r & 7)) << 3)] = v;
      }
    }
    // ---- stage B tile (64 x 64) from bf16 weights
#pragma unroll
    for (int j = 0; j < 2; ++j) {
      int idx = j * 256 + tid;
      int r = idx >> 3, u = idx & 7;
      uint4 w = *(const uint4*)&W[(size_t)(col0 + r) * 512 + k0 + u * 8];
      *(uint4*)&BL[r * 64 + ((u ^ (r & 7)) << 3)] = w;
    }
    __syncthreads();

    bf16x8 af[4][2], bf[2][2];
#pragma unroll
    for (int mf = 0; mf < 4; ++mf)
#pragma unroll
      for (int ks = 0; ks < 2; ++ks) {
        int row = wm * 64 + mf * 16 + lr;
        af[mf][ks] = *(const bf16x8*)&AL[row * 64 + (((ks * 4 + lg) ^ (lr & 7)) << 3)];
      }
#pragma unroll
    for (int nf = 0; nf < 2; ++nf)
#pragma unroll
      for (int ks = 0; ks < 2; ++ks) {
        int col = wn * 32 + nf * 16 + lr;
        bf[nf][ks] = *(const bf16x8*)&BL[col * 64 + (((ks * 4 + lg) ^ (lr & 7)) << 3)];
      }
#pragma unroll
    for (int mf = 0; mf < 4; ++mf)
#pragma unroll
      for (int nf = 0; nf < 2; ++nf)
#pragma unroll
        for (int ks = 0; ks < 2; ++ks)
          acc[mf][nf] = __builtin_amdgcn_mfma_f32_16x16x32_bf16(
              af[mf][ks], bf[nf][ks], acc[mf][nf], 0, 0, 0);
  }

#pragma unroll
  for (int mf = 0; mf < 4; ++mf)
#pragma unroll
    for (int nf = 0; nf < 2; ++nf) {
      int col = col0 + wn * 32 + nf * 16 + lr;
      float bv = (bias != nullptr) ? bias[col] : 0.f;
#pragma unroll
      for (int reg = 0; reg < 4; ++reg) {
        int n = row0 + wm * 64 + mf * 16 + lg * 4 + reg;
        float val = acc[mf][nf][reg] + bv;
        if (MODE == 0) {
          int bI = n >> 10, t = n & 1023, hI = col >> 6, d = col & 63;
          size_t off = ((size_t)(bI * 8 + hI) * 1024 + t) * 64 + d;
          if constexpr (sizeof(OT) == 2) out[off] = (OT)f2bf(val);
          else out[off] = (OT)val;
        } else {
          out[(size_t)n * 512 + col] = (OT)val;
        }
      }
    }
}

// ---------------------------------------------------------------------------
// Fused flash attention, bf16 MFMA. Block: 128 q-rows of one (b,h); 4 waves
// x 32 rows. Scores = Q'(128d) . K|P, online softmax w/ packed mask bits,
// O = P.V via LDS round-trip of P + transposed-swizzled V. Out: bf16 (B,T,512).
// ---------------------------------------------------------------------------
__global__ __launch_bounds__(256) void attn_mfma(
    const unsigned short* __restrict__ Q, const unsigned short* __restrict__ K,
    const unsigned short* __restrict__ P, const unsigned short* __restrict__ V,
    const unsigned long long* __restrict__ bits,
    const float* __restrict__ ubias, const float* __restrict__ vbias,
    unsigned short* __restrict__ X)
{
  __shared__ unsigned short KL[64 * 128];   // K|P tile, swizzled
  __shared__ unsigned short VtL[64 * 64];   // V^T tile, swizzled
  __shared__ unsigned short PL[4 * 32 * 72]; // per-wave P staging (pad 72)

  const int tid = threadIdx.x;
  const int lane = tid & 63, wq = tid >> 6;
  const int lg = lane >> 4, lr = lane & 15;
  const int bh = blockIdx.y, b = bh >> 3, h = bh & 7;
  const int tw = blockIdx.x * 128 + wq * 32;

  // ---- Q' A-fragments in registers: (q+u | q+v) * 0.125
  bf16x8 qa[2][4];
#pragma unroll
  for (int mf = 0; mf < 2; ++mf) {
    const unsigned short* qrow = Q + ((size_t)bh * 1024 + tw + mf * 16 + lr) * 64;
    uint4 qlo = *(const uint4*)&qrow[lg * 8];
    uint4 qhi = *(const uint4*)&qrow[32 + lg * 8];
#pragma unroll
    for (int ks = 0; ks < 4; ++ks) {
      int d0 = (ks & 1) * 32 + lg * 8;
      const float* bb = (ks < 2) ? (ubias + h * 64) : (vbias + h * 64);
      float4 b0 = *(const float4*)&bb[d0];
      float4 b1 = *(const float4*)&bb[d0 + 4];
      uint4 qq = (ks & 1) ? qhi : qlo;
      unsigned int qw[4] = {qq.x, qq.y, qq.z, qq.w};
      float bbv[8] = {b0.x, b0.y, b0.z, b0.w, b1.x, b1.y, b1.z, b1.w};
      bf16x8 a;
#pragma unroll
      for (int e = 0; e < 8; ++e) {
        unsigned short qb = (e & 1) ? (unsigned short)(qw[e >> 1] >> 16)
                                    : (unsigned short)(qw[e >> 1] & 0xffffu);
        a[e] = (short)f2bf((bf2f(qb) + bbv[e]) * 0.125f);
      }
      qa[mf][ks] = a;
    }
  }

  f32x4 Ofr[2][4];
  float m_[2][4], l_[2][4];
#pragma unroll
  for (int mf = 0; mf < 2; ++mf) {
#pragma unroll
    for (int nf = 0; nf < 4; ++nf) { f32x4 z = {0.f,0.f,0.f,0.f}; Ofr[mf][nf] = z; }
#pragma unroll
    for (int r = 0; r < 4; ++r) { m_[mf][r] = -3.4e38f; l_[mf][r] = 0.f; }
  }

  const unsigned short* Kg = K + (size_t)bh * 65536;
  const unsigned short* Pg = P + (size_t)h * 65536;
  const unsigned short* Vg = V + (size_t)bh * 65536;
  const unsigned long long* brow = bits + (size_t)b * 16384;
  unsigned short* Pl = PL + wq * (32 * 72);

  for (int s0t = 0; s0t < 16; ++s0t) {
    const int s0 = s0t * 64;
    __syncthreads();
    // stage K|P (64 rows x 128 cols bf16, unit-XOR swizzle)
#pragma unroll
    for (int j = 0; j < 4; ++j) {
      int idx = j * 256 + tid;
      int r = idx >> 4, c = idx & 15;
      uint4 v = (c < 8) ? *(const uint4*)&Kg[(size_t)(s0 + r) * 64 + c * 8]
                        : *(const uint4*)&Pg[(size_t)(s0 + r) * 64 + (c - 8) * 8];
      *(uint4*)&KL[r * 128 + ((c ^ (r & 7)) << 3)] = v;
    }
    // stage V^T (64 d x 64 s, swizzled)
#pragma unroll
    for (int j = 0; j < 2; ++j) {
      int idx = j * 256 + tid;
      int s = idx >> 3, dc = idx & 7;
      uint4 v = *(const uint4*)&Vg[(size_t)(s0 + s) * 64 + dc * 8];
      unsigned int w[4] = {v.x, v.y, v.z, v.w};
#pragma unroll
      for (int e = 0; e < 8; ++e) {
        int d = dc * 8 + e;
        unsigned short val = (e & 1) ? (unsigned short)(w[e >> 1] >> 16)
                                     : (unsigned short)(w[e >> 1] & 0xffffu);
        VtL[d * 64 + (((s >> 3) ^ (d & 7)) << 3) + (s & 7)] = val;
      }
    }
    __syncthreads();

    // mask words (1 u64 per owned q-row, covers this 64-wide s tile)
    unsigned long long mw[2][4];
#pragma unroll
    for (int mf = 0; mf < 2; ++mf)
#pragma unroll
      for (int r = 0; r < 4; ++r)
        mw[mf][r] = brow[(size_t)(tw + mf * 16 + lg * 4 + r) * 16 + s0t];

    // QK^T (+relpos): S = Q' . (K|P)^T
    f32x4 S[2][4];
#pragma unroll
    for (int nf = 0; nf < 4; ++nf) {
      bf16x8 kb[4];
#pragma unroll
      for (int ks = 0; ks < 4; ++ks)
        kb[ks] = *(const bf16x8*)&KL[(nf * 16 + lr) * 128 + (((ks * 4 + lg) ^ (lr & 7)) << 3)];
#pragma unroll
      for (int mf = 0; mf < 2; ++mf) {
        f32x4 a = {0.f, 0.f, 0.f, 0.f};
#pragma unroll
        for (int ks = 0; ks < 4; ++ks)
          a = __builtin_amdgcn_mfma_f32_16x16x32_bf16(qa[mf][ks], kb[ks], a, 0, 0, 0);
        S[mf][nf] = a;
      }
    }

    // online softmax update (row stats via shfl within 16-lane groups)
#pragma unroll
    for (int mf = 0; mf < 2; ++mf)
#pragma unroll
      for (int r = 0; r < 4; ++r) {
        float v = fmaxf(fmaxf(S[mf][0][r], S[mf][1][r]), fmaxf(S[mf][2][r], S[mf][3][r]));
        v = fmaxf(v, __shfl_xor(v, 1));
        v = fmaxf(v, __shfl_xor(v, 2));
        v = fmaxf(v, __shfl_xor(v, 4));
        v = fmaxf(v, __shfl_xor(v, 8));
        float mo = m_[mf][r];
        float mn = fmaxf(mo, v);
        m_[mf][r] = mn;
        float sc = __expf(mo - mn);
        l_[mf][r] *= sc;
#pragma unroll
        for (int nf = 0; nf < 4; ++nf) Ofr[mf][nf][r] *= sc;
        float ps = 0.f;
#pragma unroll
        for (int nf = 0; nf < 4; ++nf) {
          float e = __expf(S[mf][nf][r] - mn);
          e = ((mw[mf][r] >> (nf * 16 + lr)) & 1ull) ? e : 0.f;
          S[mf][nf][r] = e;
          ps += e;
        }
        ps += __shfl_xor(ps, 1);
        ps += __shfl_xor(ps, 2);
        ps += __shfl_xor(ps, 4);
        ps += __shfl_xor(ps, 8);
        l_[mf][r] += ps;
      }

    // P -> per-wave LDS (bf16), then read back as A-fragments
#pragma unroll
    for (int mf = 0; mf < 2; ++mf)
#pragma unroll
      for (int nf = 0; nf < 4; ++nf)
#pragma unroll
        for (int r = 0; r < 4; ++r)
          Pl[(mf * 16 + lg * 4 + r) * 72 + nf * 16 + lr] = f2bf(S[mf][nf][r]);
    __syncthreads();

    bf16x8 pa[2][2];
#pragma unroll
    for (int mf = 0; mf < 2; ++mf)
#pragma unroll
      for (int k2 = 0; k2 < 2; ++k2)
        pa[mf][k2] = *(const bf16x8*)&Pl[(mf * 16 + lr) * 72 + k2 * 32 + lg * 8];
#pragma unroll
    for (int nf2 = 0; nf2 < 4; ++nf2) {
      int d = nf2 * 16 + lr;
      bf16x8 vb[2];
#pragma unroll
      for (int k2 = 0; k2 < 2; ++k2)
        vb[k2] = *(const bf16x8*)&VtL[d * 64 + (((k2 * 4 + lg) ^ (d & 7)) << 3)];
#pragma unroll
      for (int mf = 0; mf < 2; ++mf)
#pragma unroll
        for (int k2 = 0; k2 < 2; ++k2)
          Ofr[mf][nf2] = __builtin_amdgcn_mfma_f32_16x16x32_bf16(
              pa[mf][k2], vb[k2], Ofr[mf][nf2], 0, 0, 0);
    }
  }

  // epilogue: O / l  (l==0 -> 0), write bf16 (B,T,512)
#pragma unroll
  for (int mf = 0; mf < 2; ++mf)
#pragma unroll
    for (int r = 0; r < 4; ++r) {
      float l = l_[mf][r];
      float inv = (l > 0.f) ? 1.f / l : 0.f;
      int t = tw + mf * 16 + lg * 4 + r;
#pragma unroll
      for (int nf2 = 0; nf2 < 4; ++nf2)
        X[((size_t)b * 1024 + t) * 512 + h * 64 + nf2 * 16 + lr] =
            f2bf(Ofr[mf][nf2][r] * inv);
    }
}

extern "C" void kernel_launch(void* const* d_in, const int* in_sizes, int n_in,
                              void* d_out, int out_size, void* d_ws, size_t ws_size,
                              hipStream_t stream) {
  const float* query = (const float*)d_in[0];
  const float* key   = (const float*)d_in[1];
  const float* value = (const float*)d_in[2];
  const int*   mask  = (const int*)d_in[3];
  const float* pos   = (const float*)d_in[4];
  const float* Wq = (const float*)d_in[5];
  const float* bq = (const float*)d_in[6];
  const float* Wk = (const float*)d_in[7];
  const float* bk = (const float*)d_in[8];
  const float* Wv = (const float*)d_in[9];
  const float* bv = (const float*)d_in[10];
  const float* Wp = (const float*)d_in[11];
  const float* Wo = (const float*)d_in[12];
  const float* bo = (const float*)d_in[13];
  const float* ub = (const float*)d_in[14];
  const float* vb = (const float*)d_in[15];
  float* out = (float*)d_out;

  char* w = (char*)d_ws;
  auto alloc = [&](size_t bytes) {
    char* p = w; w += (bytes + 255) & ~(size_t)255; return p;
  };
  const size_t NA = (size_t)8 * 1024 * 512;      // activation elems (B,T,F)
  const size_t NW = (size_t)512 * 512;           // weight elems
  const size_t NP = (size_t)1024 * 512;          // pos elems

  // total ws usage: 3*8 + 1 + 8 + 1 + 5*0.5 MB  ~= 36.5 MB
  unsigned short* wsQ = (unsigned short*)alloc(NA * 2);        // (B,H,T,D) bf16
  unsigned short* wsK = (unsigned short*)alloc(NA * 2);
  unsigned short* wsV = (unsigned short*)alloc(NA * 2);
  unsigned short* wsP = (unsigned short*)alloc(NP * 2);        // (H,T,D) bf16
  unsigned short* wsX = (unsigned short*)alloc(NA * 2);        // (B,T,512) bf16
  unsigned long long* bitsW = (unsigned long long*)alloc((size_t)8 * 1024 * 16 * 8);
  unsigned short* Wqb = (unsigned short*)alloc(NW * 2);
  unsigned short* Wkb = (unsigned short*)alloc(NW * 2);
  unsigned short* Wvb = (unsigned short*)alloc(NW * 2);
  unsigned short* Wpb = (unsigned short*)alloc(NW * 2);
  unsigned short* Wob = (unsigned short*)alloc(NW * 2);

  CvtWArgs ca;
  ca.s[0] = Wq; ca.d[0] = Wqb;
  ca.s[1] = Wk; ca.d[1] = Wkb;
  ca.s[2] = Wv; ca.d[2] = Wvb;
  ca.s[3] = Wp; ca.d[3] = Wpb;
  ca.s[4] = Wo; ca.d[4] = Wob;

  dim3 blk(256);
  cvt_w<<<dim3(128, 5), blk, 0, stream>>>(ca);
  pack_mask<<<dim3(32768), blk, 0, stream>>>(mask, bitsW);
  proj_mfma<1, unsigned short, 0><<<dim3(64, 8), blk, 0, stream>>>(query, Wqb, bq, wsQ);
  proj_mfma<1, unsigned short, 0><<<dim3(64, 8), blk, 0, stream>>>(key,   Wkb, bk, wsK);
  proj_mfma<1, unsigned short, 0><<<dim3(64, 8), blk, 0, stream>>>(value, Wvb, bv, wsV);
  proj_mfma<1, unsigned short, 0><<<dim3(8, 8),  blk, 0, stream>>>(pos,   Wpb, nullptr, wsP);
  attn_mfma<<<dim3(8, 64), blk, 0, stream>>>(wsQ, wsK, wsP, wsV, bitsW, ub, vb, wsX);
  proj_mfma<0, float, 1><<<dim3(64, 8), blk, 0, stream>>>(wsX, Wob, bo, out);
}

// Round 9
// 310.309 us; speedup vs baseline: 4.2751x; 1.0108x over previous
//
#include <hip/hip_runtime.h>

typedef float f32x4 __attribute__((ext_vector_type(4)));
typedef short bf16x8 __attribute__((ext_vector_type(8)));
typedef unsigned short u16x8 __attribute__((ext_vector_type(8)));

__device__ __forceinline__ unsigned short f2bf(float f) {
  union { float f; unsigned int u; } c; c.f = f;
  unsigned int r = (c.u + 0x7fffu + ((c.u >> 16) & 1u)) >> 16;
  return (unsigned short)r;
}
__device__ __forceinline__ float bf2f(unsigned short u) {
  union { unsigned int u; float f; } c; c.u = ((unsigned int)u) << 16;
  return c.f;
}

// ---------------------------------------------------------------------------
// fp32 -> bf16 weight conversion, 5 segments (Wq,Wk,Wv,Wp,Wo), 512x512 each
// ---------------------------------------------------------------------------
struct CvtWArgs {
  const float* s[5];
  unsigned short* d[5];
};

__global__ __launch_bounds__(256) void cvt_w(CvtWArgs a) {
  const int seg = blockIdx.y;
  const float* __restrict__ src = a.s[seg];
  unsigned short* __restrict__ dst = a.d[seg];
  int i = (blockIdx.x * 256 + threadIdx.x) * 8;   // grid.x=128 -> exact
  float4 v0 = *(const float4*)&src[i];
  float4 v1 = *(const float4*)&src[i + 4];
  u16x8 o;
  o[0] = f2bf(v0.x); o[1] = f2bf(v0.y); o[2] = f2bf(v0.z); o[3] = f2bf(v0.w);
  o[4] = f2bf(v1.x); o[5] = f2bf(v1.y); o[6] = f2bf(v1.z); o[7] = f2bf(v1.w);
  *(u16x8*)&dst[i] = o;
}

// ---------------------------------------------------------------------------
// mask (int32, B*T*T) -> packed bits (1 = keep)
// ---------------------------------------------------------------------------
__global__ __launch_bounds__(256) void pack_mask(const int* __restrict__ mask,
                                                 unsigned long long* __restrict__ bits) {
  size_t i = (size_t)blockIdx.x * 256 + threadIdx.x;
  unsigned long long b = __ballot(mask[i] != 0);
  if ((threadIdx.x & 63) == 0) bits[i >> 6] = b;
}

// ---------------------------------------------------------------------------
// bf16 MFMA projection GEMM: out = X(M,512) @ W(512,512)^T (+bias)
// tile 128x64, 8 waves (4x2), wave tile 32x32, BK=64, XOR-swizzled LDS.
// IN_FP32: X fp32 (converted during staging) else bf16.
// MODE 0: out[((b*8+h)*1024+t)*64+d]  (B,H,T,D)
// MODE 1: out[n*512 + col]            row-major (M,512)
// MODE 2: out[((b*8+h)*64+d)*1024+t]  V^T layout, via LDS transpose epilogue
// ---------------------------------------------------------------------------
template <int IN_FP32, typename OT, int MODE>
__global__ __launch_bounds__(512) void proj_mfma(
    const void* __restrict__ Xv, const unsigned short* __restrict__ W,
    const float* __restrict__ bias, OT* __restrict__ out)
{
  __shared__ unsigned short SM[128 * 64 + 64 * 64];   // AL | BL (contiguous)
  unsigned short* AL = SM;
  unsigned short* BL = SM + 128 * 64;
  const int tid = threadIdx.x;
  const int lane = tid & 63, wv = tid >> 6;
  const int lg = lane >> 4, lr = lane & 15;
  const int wm = wv >> 1, wn = wv & 1;                // 4 x 2 wave grid
  const int row0 = blockIdx.x * 128, col0 = blockIdx.y * 64;

  f32x4 acc[2][2];
#pragma unroll
  for (int i = 0; i < 2; ++i)
#pragma unroll
    for (int j = 0; j < 2; ++j) { f32x4 z = {0.f,0.f,0.f,0.f}; acc[i][j] = z; }

  for (int k0 = 0; k0 < 512; k0 += 64) {
    __syncthreads();
    // ---- stage A (128 x 64), swizzle unit u -> u ^ (r&7)
    if constexpr (IN_FP32) {
      const float* X = (const float*)Xv;
#pragma unroll
      for (int j = 0; j < 2; ++j) {
        int idx = j * 512 + tid;
        int r = idx >> 3, u = idx & 7;
        const float* p = &X[(size_t)(row0 + r) * 512 + k0 + u * 8];
        float4 x0 = *(const float4*)p;
        float4 x1 = *(const float4*)(p + 4);
        u16x8 o;
        o[0] = f2bf(x0.x); o[1] = f2bf(x0.y); o[2] = f2bf(x0.z); o[3] = f2bf(x0.w);
        o[4] = f2bf(x1.x); o[5] = f2bf(x1.y); o[6] = f2bf(x1.z); o[7] = f2bf(x1.w);
        *(u16x8*)&AL[r * 64 + ((u ^ (r & 7)) << 3)] = o;
      }
    } else {
      const unsigned short* X = (const unsigned short*)Xv;
#pragma unroll
      for (int j = 0; j < 2; ++j) {
        int idx = j * 512 + tid;
        int r = idx >> 3, u = idx & 7;
        uint4 v = *(const uint4*)&X[(size_t)(row0 + r) * 512 + k0 + u * 8];
        *(uint4*)&AL[r * 64 + ((u ^ (r & 7)) << 3)] = v;
      }
    }
    // ---- stage B (64 x 64)
    {
      int r = tid >> 3, u = tid & 7;
      uint4 w = *(const uint4*)&W[(size_t)(col0 + r) * 512 + k0 + u * 8];
      *(uint4*)&BL[r * 64 + ((u ^ (r & 7)) << 3)] = w;
    }
    __syncthreads();

    bf16x8 af[2][2], bf[2][2];
#pragma unroll
    for (int mf = 0; mf < 2; ++mf)
#pragma unroll
      for (int ks = 0; ks < 2; ++ks) {
        int row = wm * 32 + mf * 16 + lr;
        af[mf][ks] = *(const bf16x8*)&AL[row * 64 + (((ks * 4 + lg) ^ (lr & 7)) << 3)];
      }
#pragma unroll
    for (int nf = 0; nf < 2; ++nf)
#pragma unroll
      for (int ks = 0; ks < 2; ++ks) {
        int col = wn * 32 + nf * 16 + lr;
        bf[nf][ks] = *(const bf16x8*)&BL[col * 64 + (((ks * 4 + lg) ^ (lr & 7)) << 3)];
      }
#pragma unroll
    for (int mf = 0; mf < 2; ++mf)
#pragma unroll
      for (int nf = 0; nf < 2; ++nf)
#pragma unroll
        for (int ks = 0; ks < 2; ++ks)
          acc[mf][nf] = __builtin_amdgcn_mfma_f32_16x16x32_bf16(
              af[mf][ks], bf[nf][ks], acc[mf][nf], 0, 0, 0);
  }

  if constexpr (MODE == 2) {
    // ---- transpose epilogue via LDS (pad 73 -> conflict-free-ish)
    unsigned short* TL = SM;                          // [128][73], 18688 B
    __syncthreads();
#pragma unroll
    for (int mf = 0; mf < 2; ++mf)
#pragma unroll
      for (int nf = 0; nf < 2; ++nf) {
        int dl = wn * 32 + nf * 16 + lr;
        float bv = bias[col0 + dl];
#pragma unroll
        for (int reg = 0; reg < 4; ++reg) {
          int tl = wm * 32 + mf * 16 + lg * 4 + reg;
          TL[tl * 73 + dl] = f2bf(acc[mf][nf][reg] + bv);
        }
      }
    __syncthreads();
    const int bI = row0 >> 10, hI = col0 >> 6, t0 = row0 & 1023;
#pragma unroll
    for (int j = 0; j < 2; ++j) {
      int slot = j * 512 + tid;        // 1024 slots: 64 d x 16 chunks
      int d = slot >> 4, ch = slot & 15;
      u16x8 o;
#pragma unroll
      for (int e = 0; e < 8; ++e) o[e] = TL[(ch * 8 + e) * 73 + d];
      *(u16x8*)&out[((size_t)((bI * 8 + hI) * 64) + d) * 1024 + t0 + ch * 8] = o;
    }
  } else {
#pragma unroll
    for (int mf = 0; mf < 2; ++mf)
#pragma unroll
      for (int nf = 0; nf < 2; ++nf) {
        int col = col0 + wn * 32 + nf * 16 + lr;
        float bv = (bias != nullptr) ? bias[col] : 0.f;
#pragma unroll
        for (int reg = 0; reg < 4; ++reg) {
          int n = row0 + wm * 32 + mf * 16 + lg * 4 + reg;
          float val = acc[mf][nf][reg] + bv;
          if (MODE == 0) {
            int bI = n >> 10, t = n & 1023, hI = col >> 6, d = col & 63;
            size_t off = ((size_t)(bI * 8 + hI) * 1024 + t) * 64 + d;
            if constexpr (sizeof(OT) == 2) out[off] = (OT)f2bf(val);
            else out[off] = (OT)val;
          } else {
            out[(size_t)n * 512 + col] = (OT)val;
          }
        }
      }
  }
}

// ---------------------------------------------------------------------------
// Fused flash attention, bf16 MFMA. Block: 64 q-rows of one (b,h); 4 waves
// x 16 rows. V consumed pre-transposed (B,H,64,1024). Grid (16, 64).
// ---------------------------------------------------------------------------
__global__ __launch_bounds__(256) void attn_mfma(
    const unsigned short* __restrict__ Q, const unsigned short* __restrict__ K,
    const unsigned short* __restrict__ P, const unsigned short* __restrict__ Vt,
    const unsigned long long* __restrict__ bits,
    const float* __restrict__ ubias, const float* __restrict__ vbias,
    unsigned short* __restrict__ X)
{
  __shared__ unsigned short KL[64 * 128];   // K|P tile, swizzled
  __shared__ unsigned short VtL[64 * 64];   // V^T tile, swizzled
  __shared__ unsigned short PL[4 * 16 * 72]; // per-wave P staging (pad 72)

  const int tid = threadIdx.x;
  const int lane = tid & 63, wq = tid >> 6;
  const int lg = lane >> 4, lr = lane & 15;
  const int bh = blockIdx.y, b = bh >> 3, h = bh & 7;
  const int tw = blockIdx.x * 64 + wq * 16;

  // ---- Q' A-fragments: (q+u | q+v) * 0.125
  bf16x8 qa[4];
  {
    const unsigned short* qrow = Q + ((size_t)bh * 1024 + tw + lr) * 64;
    uint4 qlo = *(const uint4*)&qrow[lg * 8];
    uint4 qhi = *(const uint4*)&qrow[32 + lg * 8];
#pragma unroll
    for (int ks = 0; ks < 4; ++ks) {
      int d0 = (ks & 1) * 32 + lg * 8;
      const float* bb = (ks < 2) ? (ubias + h * 64) : (vbias + h * 64);
      float4 b0 = *(const float4*)&bb[d0];
      float4 b1 = *(const float4*)&bb[d0 + 4];
      uint4 qq = (ks & 1) ? qhi : qlo;
      unsigned int qw[4] = {qq.x, qq.y, qq.z, qq.w};
      float bbv[8] = {b0.x, b0.y, b0.z, b0.w, b1.x, b1.y, b1.z, b1.w};
      bf16x8 a;
#pragma unroll
      for (int e = 0; e < 8; ++e) {
        unsigned short qb = (e & 1) ? (unsigned short)(qw[e >> 1] >> 16)
                                    : (unsigned short)(qw[e >> 1] & 0xffffu);
        a[e] = (short)f2bf((bf2f(qb) + bbv[e]) * 0.125f);
      }
      qa[ks] = a;
    }
  }

  f32x4 Ofr[4];
  float m_[4], l_[4];
#pragma unroll
  for (int nf = 0; nf < 4; ++nf) { f32x4 z = {0.f,0.f,0.f,0.f}; Ofr[nf] = z; }
#pragma unroll
  for (int r = 0; r < 4; ++r) { m_[r] = -3.4e38f; l_[r] = 0.f; }

  const unsigned short* Kg = K + (size_t)bh * 65536;
  const unsigned short* Pg = P + (size_t)h * 65536;
  const unsigned short* Vg = Vt + (size_t)bh * 65536;   // (64 d, 1024 s)
  const unsigned long long* brow = bits + (size_t)b * 16384;
  unsigned short* Pl = PL + wq * (16 * 72);

  for (int s0t = 0; s0t < 16; ++s0t) {
    const int s0 = s0t * 64;
    __syncthreads();
    // stage K|P (64 s-rows x 128 d-cols, unit-XOR swizzle)
#pragma unroll
    for (int j = 0; j < 4; ++j) {
      int idx = j * 256 + tid;
      int r = idx >> 4, c = idx & 15;
      uint4 v = (c < 8) ? *(const uint4*)&Kg[(size_t)(s0 + r) * 64 + c * 8]
                        : *(const uint4*)&Pg[(size_t)(s0 + r) * 64 + (c - 8) * 8];
      *(uint4*)&KL[r * 128 + ((c ^ (r & 7)) << 3)] = v;
    }
    // stage V^T tile (64 d x 64 s) -- coalesced from global V^T
#pragma unroll
    for (int j = 0; j < 2; ++j) {
      int idx = j * 256 + tid;
      int d = idx >> 3, u = idx & 7;
      uint4 v = *(const uint4*)&Vg[(size_t)d * 1024 + s0 + u * 8];
      *(uint4*)&VtL[d * 64 + ((u ^ (d & 7)) << 3)] = v;
    }
    __syncthreads();

    // mask words (1 u64 per owned q-row for this 64-wide s tile)
    unsigned long long mw[4];
#pragma unroll
    for (int r = 0; r < 4; ++r)
      mw[r] = brow[(size_t)(tw + lg * 4 + r) * 16 + s0t];

    // QK^T (+relpos): S = Q' . (K|P)^T
    f32x4 S[4];
#pragma unroll
    for (int nf = 0; nf < 4; ++nf) {
      bf16x8 kb[4];
#pragma unroll
      for (int ks = 0; ks < 4; ++ks)
        kb[ks] = *(const bf16x8*)&KL[(nf * 16 + lr) * 128 + (((ks * 4 + lg) ^ (lr & 7)) << 3)];
      f32x4 a = {0.f, 0.f, 0.f, 0.f};
#pragma unroll
      for (int ks = 0; ks < 4; ++ks)
        a = __builtin_amdgcn_mfma_f32_16x16x32_bf16(qa[ks], kb[ks], a, 0, 0, 0);
      S[nf] = a;
    }

    // online softmax update (row stats via shfl within 16-lane groups)
#pragma unroll
    for (int r = 0; r < 4; ++r) {
      float v = fmaxf(fmaxf(S[0][r], S[1][r]), fmaxf(S[2][r], S[3][r]));
      v = fmaxf(v, __shfl_xor(v, 1));
      v = fmaxf(v, __shfl_xor(v, 2));
      v = fmaxf(v, __shfl_xor(v, 4));
      v = fmaxf(v, __shfl_xor(v, 8));
      float mo = m_[r];
      float mn = fmaxf(mo, v);
      m_[r] = mn;
      float sc = __expf(mo - mn);
      l_[r] *= sc;
#pragma unroll
      for (int nf = 0; nf < 4; ++nf) Ofr[nf][r] *= sc;
      float ps = 0.f;
#pragma unroll
      for (int nf = 0; nf < 4; ++nf) {
        float e = __expf(S[nf][r] - mn);
        e = ((mw[r] >> (nf * 16 + lr)) & 1ull) ? e : 0.f;
        S[nf][r] = e;
        ps += e;
      }
      ps += __shfl_xor(ps, 1);
      ps += __shfl_xor(ps, 2);
      ps += __shfl_xor(ps, 4);
      ps += __shfl_xor(ps, 8);
      l_[r] += ps;
    }

    // P -> per-wave LDS (bf16), read back as A-fragments
#pragma unroll
    for (int nf = 0; nf < 4; ++nf)
#pragma unroll
      for (int r = 0; r < 4; ++r)
        Pl[(lg * 4 + r) * 72 + nf * 16 + lr] = f2bf(S[nf][r]);
    __syncthreads();

    bf16x8 pa[2];
#pragma unroll
    for (int k2 = 0; k2 < 2; ++k2)
      pa[k2] = *(const bf16x8*)&Pl[lr * 72 + k2 * 32 + lg * 8];
#pragma unroll
    for (int nf2 = 0; nf2 < 4; ++nf2) {
      int d = nf2 * 16 + lr;
      bf16x8 vb[2];
#pragma unroll
      for (int k2 = 0; k2 < 2; ++k2)
        vb[k2] = *(const bf16x8*)&VtL[d * 64 + (((k2 * 4 + lg) ^ (d & 7)) << 3)];
#pragma unroll
      for (int k2 = 0; k2 < 2; ++k2)
        Ofr[nf2] = __builtin_amdgcn_mfma_f32_16x16x32_bf16(
            pa[k2], vb[k2], Ofr[nf2], 0, 0, 0);
    }
  }

  // epilogue: O / l  (l==0 -> 0), write bf16 (B,T,512)
#pragma unroll
  for (int r = 0; r < 4; ++r) {
    float l = l_[r];
    float inv = (l > 0.f) ? 1.f / l : 0.f;
    int t = tw + lg * 4 + r;
#pragma unroll
    for (int nf2 = 0; nf2 < 4; ++nf2)
      X[((size_t)b * 1024 + t) * 512 + h * 64 + nf2 * 16 + lr] =
          f2bf(Ofr[nf2][r] * inv);
  }
}

extern "C" void kernel_launch(void* const* d_in, const int* in_sizes, int n_in,
                              void* d_out, int out_size, void* d_ws, size_t ws_size,
                              hipStream_t stream) {
  const float* query = (const float*)d_in[0];
  const float* key   = (const float*)d_in[1];
  const float* value = (const float*)d_in[2];
  const int*   mask  = (const int*)d_in[3];
  const float* pos   = (const float*)d_in[4];
  const float* Wq = (const float*)d_in[5];
  const float* bq = (const float*)d_in[6];
  const float* Wk = (const float*)d_in[7];
  const float* bk = (const float*)d_in[8];
  const float* Wv = (const float*)d_in[9];
  const float* bv = (const float*)d_in[10];
  const float* Wp = (const float*)d_in[11];
  const float* Wo = (const float*)d_in[12];
  const float* bo = (const float*)d_in[13];
  const float* ub = (const float*)d_in[14];
  const float* vb = (const float*)d_in[15];
  float* out = (float*)d_out;

  char* w = (char*)d_ws;
  auto alloc = [&](size_t bytes) {
    char* p = w; w += (bytes + 255) & ~(size_t)255; return p;
  };
  const size_t NA = (size_t)8 * 1024 * 512;      // activation elems (B,T,F)
  const size_t NW = (size_t)512 * 512;           // weight elems
  const size_t NP = (size_t)1024 * 512;          // pos elems

  // total ws usage ~= 36.5 MB (validated fits in round 5)
  unsigned short* wsQ  = (unsigned short*)alloc(NA * 2);       // (B,H,T,D) bf16
  unsigned short* wsK  = (unsigned short*)alloc(NA * 2);
  unsigned short* wsVt = (unsigned short*)alloc(NA * 2);       // (B,H,64,1024) bf16
  unsigned short* wsP  = (unsigned short*)alloc(NP * 2);       // (H,T,D) bf16
  unsigned short* wsX  = (unsigned short*)alloc(NA * 2);       // (B,T,512) bf16
  unsigned long long* bitsW = (unsigned long long*)alloc((size_t)8 * 1024 * 16 * 8);
  unsigned short* Wqb = (unsigned short*)alloc(NW * 2);
  unsigned short* Wkb = (unsigned short*)alloc(NW * 2);
  unsigned short* Wvb = (unsigned short*)alloc(NW * 2);
  unsigned short* Wpb = (unsigned short*)alloc(NW * 2);
  unsigned short* Wob = (unsigned short*)alloc(NW * 2);

  CvtWArgs ca;
  ca.s[0] = Wq; ca.d[0] = Wqb;
  ca.s[1] = Wk; ca.d[1] = Wkb;
  ca.s[2] = Wv; ca.d[2] = Wvb;
  ca.s[3] = Wp; ca.d[3] = Wpb;
  ca.s[4] = Wo; ca.d[4] = Wob;

  cvt_w<<<dim3(128, 5), dim3(256), 0, stream>>>(ca);
  pack_mask<<<dim3(32768), dim3(256), 0, stream>>>(mask, bitsW);
  proj_mfma<1, unsigned short, 0><<<dim3(64, 8), dim3(512), 0, stream>>>(query, Wqb, bq, wsQ);
  proj_mfma<1, unsigned short, 0><<<dim3(64, 8), dim3(512), 0, stream>>>(key,   Wkb, bk, wsK);
  proj_mfma<1, unsigned short, 2><<<dim3(64, 8), dim3(512), 0, stream>>>(value, Wvb, bv, wsVt);
  proj_mfma<1, unsigned short, 0><<<dim3(8, 8),  dim3(512), 0, stream>>>(pos,   Wpb, nullptr, wsP);
  attn_mfma<<<dim3(16, 64), dim3(256), 0, stream>>>(wsQ, wsK, wsP, wsVt, bitsW, ub, vb, wsX);
  proj_mfma<0, float, 1><<<dim3(64, 8), dim3(512), 0, stream>>>(wsX, Wob, bo, out);
}